// Round 3
// baseline (4510.572 us; speedup 1.0000x reference)
//
#include <hip/hip_runtime.h>
#include <stdint.h>

typedef uint16_t u16;
typedef uint32_t u32;
typedef unsigned long long u64;
typedef __attribute__((ext_vector_type(8))) __bf16 bf16x8;
typedef __attribute__((ext_vector_type(8))) short short8;
typedef __attribute__((ext_vector_type(4))) float floatx4;
typedef __attribute__((ext_vector_type(2))) u64 u64x2;
typedef __attribute__((ext_vector_type(4))) u32 u32x4;

// ---------- helpers ----------
__device__ __forceinline__ float bf2f(u16 u) {
  union { u32 i; float f; } v; v.i = ((u32)u) << 16; return v.f;
}
__device__ __forceinline__ u16 f2bf(float f) {
  union { float f; u32 i; } v; v.f = f;
  u32 i = v.i;
  return (u16)((i + 0x7FFFu + ((i >> 16) & 1u)) >> 16); // RTNE
}
__device__ __forceinline__ float sigm(float x) { return 1.f / (1.f + __expf(-x)); }
__device__ __forceinline__ float tanh_f(float x) {
  x = fminf(15.f, fmaxf(-15.f, x));
  float e = __expf(2.f * x);
  return (e - 1.f) / (e + 1.f);
}

// ---------- fp32 -> bf16 transpose: src[R][C] f32 -> dst[C][R] bf16 ----------
__global__ void transpose_f32_bf16(const float* __restrict__ src, u16* __restrict__ dst,
                                   int R, int C) {
  __shared__ u16 tile[32][33];
  int x = blockIdx.x * 32 + threadIdx.x;
#pragma unroll
  for (int j = 0; j < 4; ++j) {
    int y = blockIdx.y * 32 + threadIdx.y + j * 8;
    if (x < C && y < R) tile[threadIdx.y + j * 8][threadIdx.x] = f2bf(src[(size_t)y * C + x]);
  }
  __syncthreads();
  int x2 = blockIdx.y * 32 + threadIdx.x;
#pragma unroll
  for (int j = 0; j < 4; ++j) {
    int y2 = blockIdx.x * 32 + threadIdx.y + j * 8;
    if (x2 < R && y2 < C) dst[(size_t)y2 * R + x2] = tile[threadIdx.x][threadIdx.y + j * 8];
  }
}

// ---------- xp GEMM: C_bf16[M,N] = A_f32[M,K] @ BT_bf16[N,K]^T + bias_f32 ----------
__global__ __launch_bounds__(256) void gemm_a32_bt(
    const float* __restrict__ A, const u16* __restrict__ BT,
    const float* __restrict__ bias, u16* __restrict__ C,
    int M, int N, int K) {
  __shared__ __align__(16) u16 As[64 * 40];
  __shared__ __align__(16) u16 Bs[64 * 40];
  const int tid = threadIdx.x;
  const int wave = tid >> 6, lane = tid & 63;
  const int q4 = lane >> 4, n16 = lane & 15;
  const int mw = (wave >> 1) * 32, nw = (wave & 1) * 32;
  const int m0 = blockIdx.y * 64, n0 = blockIdx.x * 64;
  const int ldrow = tid >> 2, ldseg = (tid & 3) * 8;

  floatx4 acc[2][2] = {};
  for (int k0 = 0; k0 < K; k0 += 32) {
    const float* ap = A + (size_t)(m0 + ldrow) * K + k0 + ldseg;
    floatx4 a0 = *(const floatx4*)ap;
    floatx4 a1 = *(const floatx4*)(ap + 4);
    short8 s;
    s[0] = (short)f2bf(a0[0]); s[1] = (short)f2bf(a0[1]);
    s[2] = (short)f2bf(a0[2]); s[3] = (short)f2bf(a0[3]);
    s[4] = (short)f2bf(a1[0]); s[5] = (short)f2bf(a1[1]);
    s[6] = (short)f2bf(a1[2]); s[7] = (short)f2bf(a1[3]);
    *(short8*)(As + ldrow * 40 + ldseg) = s;
    *(short8*)(Bs + ldrow * 40 + ldseg) =
        *(const short8*)(BT + (size_t)(n0 + ldrow) * K + k0 + ldseg);
    __syncthreads();
#pragma unroll
    for (int mi = 0; mi < 2; ++mi) {
      bf16x8 a = *(const bf16x8*)(As + (mw + mi * 16 + n16) * 40 + q4 * 8);
#pragma unroll
      for (int ni = 0; ni < 2; ++ni) {
        bf16x8 b = *(const bf16x8*)(Bs + (nw + ni * 16 + n16) * 40 + q4 * 8);
        acc[mi][ni] = __builtin_amdgcn_mfma_f32_16x16x32_bf16(a, b, acc[mi][ni], 0, 0, 0);
      }
    }
    __syncthreads();
  }
#pragma unroll
  for (int mi = 0; mi < 2; ++mi)
#pragma unroll
    for (int ni = 0; ni < 2; ++ni) {
      int col = n0 + nw + ni * 16 + n16;
      float bv = bias[col];
#pragma unroll
      for (int r = 0; r < 4; ++r) {
        int m = m0 + mw + mi * 16 + q4 * 4 + r;
        C[(size_t)m * N + col] = f2bf(acc[mi][ni][r] + bv);
      }
    }
}

// ---------- final GEMM over blocked+permuted hidden layout ----------
__global__ __launch_bounds__(256) void gemm_bt_f32out_perm(
    const u16* __restrict__ A, const u16* __restrict__ BT,
    const float* __restrict__ bias, float* __restrict__ C,
    int M, int N, int K) {
  __shared__ __align__(16) u16 As[64 * 40];
  __shared__ __align__(16) u16 Bs[64 * 40];
  const int tid = threadIdx.x;
  const int wave = tid >> 6, lane = tid & 63;
  const int q4 = lane >> 4, n16 = lane & 15;
  const int mw = (wave >> 1) * 32, nw = (wave & 1) * 32;
  const int m0 = blockIdx.y * 64, n0 = blockIdx.x * 64;
  const int ldrow = tid >> 2, ldseg = (tid & 3) * 8;

  const int mm = m0 + ldrow;
  const size_t slot = ((size_t)((mm >> 13) * 512 + ((mm & 8191) >> 4))) * 8192
                      + (mm & 15) * 16;

  floatx4 acc[2][2] = {};
  for (int k0 = 0; k0 < K; k0 += 32) {
    int kk = k0 + ldseg;
    *(short8*)(As + ldrow * 40 + ldseg) =
        *(const short8*)(A + slot + (kk >> 4) * 256 + (kk & 15));
    *(short8*)(Bs + ldrow * 40 + ldseg) =
        *(const short8*)(BT + (size_t)(n0 + ldrow) * K + k0 + ldseg);
    __syncthreads();
#pragma unroll
    for (int mi = 0; mi < 2; ++mi) {
      bf16x8 a = *(const bf16x8*)(As + (mw + mi * 16 + n16) * 40 + q4 * 8);
#pragma unroll
      for (int ni = 0; ni < 2; ++ni) {
        bf16x8 b = *(const bf16x8*)(Bs + (nw + ni * 16 + n16) * 40 + q4 * 8);
        acc[mi][ni] = __builtin_amdgcn_mfma_f32_16x16x32_bf16(a, b, acc[mi][ni], 0, 0, 0);
      }
    }
    __syncthreads();
  }
#pragma unroll
  for (int mi = 0; mi < 2; ++mi)
#pragma unroll
    for (int ni = 0; ni < 2; ++ni) {
      int col = n0 + nw + ni * 16 + n16;
      float bv = bias[col];
#pragma unroll
      for (int r = 0; r < 4; ++r) {
        int m = m0 + mw + mi * 16 + q4 * 4 + r;
        int orow = ((m >> 13) * 16 + (m & 15)) * 512 + ((m & 8191) >> 4);
        C[(size_t)orow * N + col] = acc[mi][ni][r] + bv;
      }
    }
}

// ---------- LSTM scan ----------
// 64 blocks x 256 threads; blocks with (bi&7)>=4 exit. Group g = blocks
// {g, g+8, ..., g+56}. Placement ground truth via s_getreg(HW_REG_XCC_ID):
// group enters fast mode only if all 8 blocks report the same XCD. Fast
// consumers poll MFMA A-fragments directly from the blocked global h layout
// with buffer_load_dwordx4 sc0 (L1-bypass, served by the shared XCD L2).
// HANG-PROOF invariants:
//   (a) every fast poll is BOUNDED (1024 sweeps); 3 failed polls -> wave
//       permanently degrades to agent-scope loads (always fed, see (b));
//   (b) producers ALWAYS dual-store h (plain -> local L2, agent -> fabric);
//       both stores carry the same value so any ordering is benign;
//   (c) sentinel 0xFFFF bf16 (NaN) is impossible for h = sigm*tanh, so a
//       non-sentinel u64 is always real data; the detecting load IS the data.
// RULE-18 FIX (round-2 NaN post-mortem): after the inline-asm s_waitcnt,
// every fragment register is LAUNDERED through a volatile "+v" asm before the
// sentinel check / MFMA, so neither can be hoisted above the waitcnt.
// No LDS staging, no __syncthreads in the scan loop (waves fully decoupled).
#define T_STEPS 512
__global__ __launch_bounds__(256, 1) void lstm_scan(
    const u16* __restrict__ xp,     // [64, 512, 2048] bf16
    const u16* __restrict__ UT,     // [2048, 512] bf16
    u16* __restrict__ hT_all,       // [4][512][32][16][16] bf16, sentinel-filled
    float* __restrict__ out_hT,     // [64,512] f32
    float* __restrict__ out_cT,     // [64,512] f32
    u64* __restrict__ ids) {        // [4][8] XCD ids, zero-filled
  const int bi = blockIdx.x;
  const int g = bi & 7;
  if (g >= 4) return;
  const int wgi = bi >> 3;
  const int tid = threadIdx.x;
  const int wave = tid >> 6;
  const int lane = tid & 63;
  const int n = lane & 15;
  const int q4 = lane >> 4;
  const int cb = wgi * 64 + wave * 16;   // wave's h-col base
  const int p = wgi * 4 + wave;          // tile index in group, 0..31

  __shared__ __align__(8) u16 hstw[4 * 256];   // per-wave 16x16 transpose patch
  __shared__ int s_mode;
  u16* hp = hstw + wave * 256;

  // ---- placement check: do all 8 blocks of this group share an XCD? ----
  if (tid == 0) {
    // HW_REG_XCC_ID = id 20; simm = ((32-1)<<11) | (0<<6) | 20 = 63508
    u32 xcc = ((u32)__builtin_amdgcn_s_getreg(63508)) & 0xFu;
    __hip_atomic_store(ids + g * 8 + wgi, (u64)(xcc + 1),
                       __ATOMIC_RELAXED, __HIP_MEMORY_SCOPE_AGENT);
    u64 v[8]; bool done = false;
    for (int it = 0; it < 20000 && !done; ++it) {
      done = true;
#pragma unroll
      for (int j = 0; j < 8; ++j) {
        v[j] = __hip_atomic_load(ids + g * 8 + j,
                                 __ATOMIC_RELAXED, __HIP_MEMORY_SCOPE_AGENT);
        done &= (v[j] != 0ull);
      }
    }
    bool same = done;
    if (done) {
#pragma unroll
      for (int j = 1; j < 8; ++j) same &= (v[j] == v[0]);
    }
    s_mode = same ? 0 : 1;   // 0 = fast (L2/sc0), 1 = agent
  }
  __syncthreads();
  int mode = s_mode;
  int fails = 0;

  // SRSRC over hT_all for sc0 buffer loads (32-bit voffset; 32 MiB buffer)
  u32x4 srsrc;
  {
    u64 a = (u64)(uintptr_t)hT_all;
    srsrc.x = (u32)a; srsrc.y = (u32)(a >> 32);
    srsrc.z = 33554432u; srsrc.w = 0x00020000u;
  }

  // Preload U fragments (B-operand layout)
  bf16x8 u[4][16];
#pragma unroll
  for (int qg = 0; qg < 4; ++qg) {
    const u16* up = UT + (size_t)(qg * 512 + cb + n) * 512;
#pragma unroll
    for (int kt = 0; kt < 16; ++kt)
      u[qg][kt] = *(const bf16x8*)(up + kt * 32 + q4 * 8);
  }

  float cst[4] = {0.f, 0.f, 0.f, 0.f};
  const u16* xp_base = xp + (size_t)(g * 16) * T_STEPS * 2048;
  // per-lane fragment offset inside a (g,t) slot, u16 units:
  // frag kt covers h row n, K cols kt*32 + q4*8 .. +8
  const u32 fragoff = (u32)((q4 >> 1) * 256 + n * 16 + (q4 & 1) * 8);

#pragma unroll 1
  for (int t = 0; t < T_STEPS; ++t) {
    // xp loads: independent of h_{t-1}; issue before the poll
    float xpv[4][4];
#pragma unroll
    for (int qg = 0; qg < 4; ++qg)
#pragma unroll
      for (int r = 0; r < 4; ++r)
        xpv[qg][r] = bf2f(xp_base[((size_t)(q4 * 4 + r) * T_STEPS + t) * 2048
                                  + qg * 512 + cb + n]);
    __asm__ volatile("" ::: "memory");

    floatx4 acc[4] = {};
    if (t > 0) {
      const u32 frag_u16 = (u32)(g * T_STEPS + (t - 1)) * 8192u + fragoff;
      u64x2 f[16];
      bool have = false;

      if (mode == 0) {
        // FAST: sc0 buffer loads (L1-bypass, XCD-L2-served); bounded sweeps
        int sweeps = 0;
        for (;;) {
#pragma unroll
          for (int kt = 0; kt < 16; ++kt)
            asm volatile("buffer_load_dwordx4 %0, %1, %2, 0 offen sc0"
                         : "=&v"(f[kt])
                         : "v"((frag_u16 + (u32)kt * 512u) * 2u), "s"(srsrc));
          asm volatile("s_waitcnt vmcnt(0)" ::: "memory");
          __builtin_amdgcn_sched_barrier(0);
          // launder: value-def now AFTER the waitcnt -> checks/MFMA can't hoist
#pragma unroll
          for (int kt = 0; kt < 16; ++kt)
            asm volatile("" : "+v"(f[kt]));
          bool ok = true;
#pragma unroll
          for (int kt = 0; kt < 16; ++kt)
            ok = ok & (f[kt][0] != ~0ull) & (f[kt][1] != ~0ull);
          if (__all((int)ok)) { have = true; break; }
          if (++sweeps > 1024) {              // bounded; 3 strikes -> agent
            if (++fails >= 3) mode = 1;
            break;
          }
        }
      }
      if (!have) {
        // AGENT: guaranteed by producers' agent stores; always terminates
        const u64* hb = (const u64*)hT_all + (size_t)(frag_u16 >> 2);
        for (;;) {
          u64 lo[16], hi[16];
#pragma unroll
          for (int kt = 0; kt < 16; ++kt) {
            lo[kt] = __hip_atomic_load(hb + kt * 128,
                                       __ATOMIC_RELAXED, __HIP_MEMORY_SCOPE_AGENT);
            hi[kt] = __hip_atomic_load(hb + kt * 128 + 1,
                                       __ATOMIC_RELAXED, __HIP_MEMORY_SCOPE_AGENT);
          }
          bool ok = true;
#pragma unroll
          for (int kt = 0; kt < 16; ++kt)
            ok = ok & (lo[kt] != ~0ull) & (hi[kt] != ~0ull);
          if (__all((int)ok)) {
#pragma unroll
            for (int kt = 0; kt < 16; ++kt) { f[kt][0] = lo[kt]; f[kt][1] = hi[kt]; }
            break;
          }
        }
      }
      __asm__ volatile("" ::: "memory");

#pragma unroll
      for (int kt = 0; kt < 16; ++kt) {
        bf16x8 a = __builtin_bit_cast(bf16x8, f[kt]);
        acc[0] = __builtin_amdgcn_mfma_f32_16x16x32_bf16(a, u[0][kt], acc[0], 0, 0, 0);
        acc[1] = __builtin_amdgcn_mfma_f32_16x16x32_bf16(a, u[1][kt], acc[1], 0, 0, 0);
        acc[2] = __builtin_amdgcn_mfma_f32_16x16x32_bf16(a, u[2][kt], acc[2], 0, 0, 0);
        acc[3] = __builtin_amdgcn_mfma_f32_16x16x32_bf16(a, u[3][kt], acc[3], 0, 0, 0);
      }
    }

    // gates + state update (C-layout: row=q4*4+r, col=n within wave tile)
#pragma unroll
    for (int r = 0; r < 4; ++r) {
      float gi = sigm(acc[0][r] + xpv[0][r]);
      float gf = sigm(acc[1][r] + xpv[1][r]);
      float gg = tanh_f(acc[2][r] + xpv[2][r]);
      float go = sigm(acc[3][r] + xpv[3][r]);
      float cn = gf * cst[r] + gi * gg;
      cst[r] = cn;
      float hv = go * tanh_f(cn);
      int row = q4 * 4 + r;
      hp[row * 16 + n] = f2bf(hv);    // wave-private LDS transpose patch
      if (t == T_STEPS - 1) {
        out_hT[(g * 16 + row) * 512 + cb + n] = hv;
        out_cT[(g * 16 + row) * 512 + cb + n] = cn;
      }
    }
    __asm__ volatile("s_waitcnt lgkmcnt(0)" ::: "memory"); // patch visible wave-wide

    // DUAL store of own 16x16 tile (64 lanes x u64 = 512 B contiguous):
    // plain -> local L2 (feeds sc0 readers), agent -> fabric (feeds agent
    // readers). Same value both ways -> any ordering/eviction is benign.
    {
      u64 v = *(const u64*)(hp + (lane >> 2) * 16 + (lane & 3) * 4);
      u64* hdst = (u64*)(hT_all) + (size_t)(g * T_STEPS + t) * 2048 + p * 64 + lane;
      asm volatile("global_store_dwordx2 %0, %1, off" :: "v"(hdst), "v"(v) : "memory");
      __hip_atomic_store(hdst, v, __ATOMIC_RELAXED, __HIP_MEMORY_SCOPE_AGENT);
    }
  }
}

// ---------- launch ----------
extern "C" void kernel_launch(void* const* d_in, const int* in_sizes, int n_in,
                              void* d_out, int out_size, void* d_ws, size_t ws_size,
                              hipStream_t stream) {
  (void)in_sizes; (void)n_in; (void)out_size; (void)ws_size;
  const float* x    = (const float*)d_in[0]; // [64,512,256] f32
  const float* W    = (const float*)d_in[1]; // [256,2048] f32
  const float* U    = (const float*)d_in[2]; // [512,2048] f32
  const float* bias = (const float*)d_in[3]; // [2048] f32
  const float* Wl   = (const float*)d_in[4]; // [512,256] f32
  const float* bl   = (const float*)d_in[5]; // [256] f32
  float* out = (float*)d_out;                // [64,512,256] ++ hT[64,512] ++ cT[64,512]
  char* ws = (char*)d_ws;

  u16* xp     = (u16*)(ws + 0);            // 134,217,728 B
  u16* UT     = (u16*)(ws + 134217728);    //   2,097,152 B
  u16* WT     = (u16*)(ws + 136314880);    //   1,048,576 B
  u16* WlT    = (u16*)(ws + 137363456);    //     262,144 B
  u16* hT_all = (u16*)(ws + 137625600);    //  33,554,432 B  [4][512][32][16][16]

  // sentinel-fill h slots (0xFFFF bf16 = NaN, impossible as an h value).
  // ids (256 B) live at the FRONT of the out buffer (zero = unwritten):
  // overwritten later by the final GEMM, so no extra workspace is consumed.
  hipMemsetAsync(hT_all, 0xFF, 33554432, stream);
  hipMemsetAsync(out, 0x00, 512, stream);

  transpose_f32_bf16<<<dim3(2048 / 32, 256 / 32), dim3(32, 8), 0, stream>>>(W, WT, 256, 2048);
  transpose_f32_bf16<<<dim3(2048 / 32, 512 / 32), dim3(32, 8), 0, stream>>>(U, UT, 512, 2048);
  transpose_f32_bf16<<<dim3(256 / 32, 512 / 32), dim3(32, 8), 0, stream>>>(Wl, WlT, 512, 256);

  // x_proj = x @ W + bias : [32768,256] x [256,2048] -> bf16
  gemm_a32_bt<<<dim3(2048 / 64, 32768 / 64), 256, 0, stream>>>(x, WT, bias, xp, 32768, 2048, 256);

  // sequential LSTM scan: 64 blocks, group g = {g, g+8, ...}; blocks with
  // (bi&7)>=4 exit immediately.
  lstm_scan<<<64, 256, 0, stream>>>(xp, UT, hT_all,
                                    out + 8388608, out + 8421376, (u64*)out);

  // out = hseq @ Wl + bl, reading blocked layout, remapping output rows
  gemm_bt_f32out_perm<<<dim3(256 / 64, 32768 / 64), 256, 0, stream>>>(
      hT_all, WlT, bl, out, 32768, 256, 512);
}

// Round 4
// 1498.941 us; speedup vs baseline: 3.0092x; 3.0092x over previous
//
#include <hip/hip_runtime.h>
#include <stdint.h>

typedef uint16_t u16;
typedef uint32_t u32;
typedef unsigned long long u64;
typedef __attribute__((ext_vector_type(8))) __bf16 bf16x8;
typedef __attribute__((ext_vector_type(8))) short short8;
typedef __attribute__((ext_vector_type(4))) float floatx4;

// ---------- helpers ----------
__device__ __forceinline__ float bf2f(u16 u) {
  union { u32 i; float f; } v; v.i = ((u32)u) << 16; return v.f;
}
__device__ __forceinline__ u16 f2bf(float f) {
  union { float f; u32 i; } v; v.f = f;
  u32 i = v.i;
  return (u16)((i + 0x7FFFu + ((i >> 16) & 1u)) >> 16); // RTNE
}
__device__ __forceinline__ float sigm(float x) { return 1.f / (1.f + __expf(-x)); }
__device__ __forceinline__ float tanh_f(float x) {
  x = fminf(15.f, fmaxf(-15.f, x));
  float e = __expf(2.f * x);
  return (e - 1.f) / (e + 1.f);
}

// ---------- fp32 -> bf16 transpose: src[R][C] f32 -> dst[C][R] bf16 ----------
__global__ void transpose_f32_bf16(const float* __restrict__ src, u16* __restrict__ dst,
                                   int R, int C) {
  __shared__ u16 tile[32][33];
  int x = blockIdx.x * 32 + threadIdx.x;
#pragma unroll
  for (int j = 0; j < 4; ++j) {
    int y = blockIdx.y * 32 + threadIdx.y + j * 8;
    if (x < C && y < R) tile[threadIdx.y + j * 8][threadIdx.x] = f2bf(src[(size_t)y * C + x]);
  }
  __syncthreads();
  int x2 = blockIdx.y * 32 + threadIdx.x;
#pragma unroll
  for (int j = 0; j < 4; ++j) {
    int y2 = blockIdx.x * 32 + threadIdx.y + j * 8;
    if (x2 < R && y2 < C) dst[(size_t)y2 * R + x2] = tile[threadIdx.x][threadIdx.y + j * 8];
  }
}

// ---------- xp GEMM: C_bf16[M,N] = A_f32[M,K] @ BT_bf16[N,K]^T + bias_f32 ----------
__global__ __launch_bounds__(256) void gemm_a32_bt(
    const float* __restrict__ A, const u16* __restrict__ BT,
    const float* __restrict__ bias, u16* __restrict__ C,
    int M, int N, int K) {
  __shared__ __align__(16) u16 As[64 * 40];
  __shared__ __align__(16) u16 Bs[64 * 40];
  const int tid = threadIdx.x;
  const int wave = tid >> 6, lane = tid & 63;
  const int q4 = lane >> 4, n16 = lane & 15;
  const int mw = (wave >> 1) * 32, nw = (wave & 1) * 32;
  const int m0 = blockIdx.y * 64, n0 = blockIdx.x * 64;
  const int ldrow = tid >> 2, ldseg = (tid & 3) * 8;

  floatx4 acc[2][2] = {};
  for (int k0 = 0; k0 < K; k0 += 32) {
    const float* ap = A + (size_t)(m0 + ldrow) * K + k0 + ldseg;
    floatx4 a0 = *(const floatx4*)ap;
    floatx4 a1 = *(const floatx4*)(ap + 4);
    short8 s;
    s[0] = (short)f2bf(a0[0]); s[1] = (short)f2bf(a0[1]);
    s[2] = (short)f2bf(a0[2]); s[3] = (short)f2bf(a0[3]);
    s[4] = (short)f2bf(a1[0]); s[5] = (short)f2bf(a1[1]);
    s[6] = (short)f2bf(a1[2]); s[7] = (short)f2bf(a1[3]);
    *(short8*)(As + ldrow * 40 + ldseg) = s;
    *(short8*)(Bs + ldrow * 40 + ldseg) =
        *(const short8*)(BT + (size_t)(n0 + ldrow) * K + k0 + ldseg);
    __syncthreads();
#pragma unroll
    for (int mi = 0; mi < 2; ++mi) {
      bf16x8 a = *(const bf16x8*)(As + (mw + mi * 16 + n16) * 40 + q4 * 8);
#pragma unroll
      for (int ni = 0; ni < 2; ++ni) {
        bf16x8 b = *(const bf16x8*)(Bs + (nw + ni * 16 + n16) * 40 + q4 * 8);
        acc[mi][ni] = __builtin_amdgcn_mfma_f32_16x16x32_bf16(a, b, acc[mi][ni], 0, 0, 0);
      }
    }
    __syncthreads();
  }
#pragma unroll
  for (int mi = 0; mi < 2; ++mi)
#pragma unroll
    for (int ni = 0; ni < 2; ++ni) {
      int col = n0 + nw + ni * 16 + n16;
      float bv = bias[col];
#pragma unroll
      for (int r = 0; r < 4; ++r) {
        int m = m0 + mw + mi * 16 + q4 * 4 + r;
        C[(size_t)m * N + col] = f2bf(acc[mi][ni][r] + bv);
      }
    }
}

// ---------- final GEMM over blocked+permuted hidden layout ----------
// A'row m: g=m>>13, t=(m&8191)>>4, r=m&15. Slot (g,t) = [32 tiles][16 r][16 c] u16;
// element k at (k>>4)*256 + r*16 + (k&15). Output row = (g*16+r)*512 + t.
__global__ __launch_bounds__(256) void gemm_bt_f32out_perm(
    const u16* __restrict__ A, const u16* __restrict__ BT,
    const float* __restrict__ bias, float* __restrict__ C,
    int M, int N, int K) {
  __shared__ __align__(16) u16 As[64 * 40];
  __shared__ __align__(16) u16 Bs[64 * 40];
  const int tid = threadIdx.x;
  const int wave = tid >> 6, lane = tid & 63;
  const int q4 = lane >> 4, n16 = lane & 15;
  const int mw = (wave >> 1) * 32, nw = (wave & 1) * 32;
  const int m0 = blockIdx.y * 64, n0 = blockIdx.x * 64;
  const int ldrow = tid >> 2, ldseg = (tid & 3) * 8;

  const int mm = m0 + ldrow;
  const size_t slot = ((size_t)((mm >> 13) * 512 + ((mm & 8191) >> 4))) * 8192
                      + (mm & 15) * 16;

  floatx4 acc[2][2] = {};
  for (int k0 = 0; k0 < K; k0 += 32) {
    int kk = k0 + ldseg;
    *(short8*)(As + ldrow * 40 + ldseg) =
        *(const short8*)(A + slot + (kk >> 4) * 256 + (kk & 15));
    *(short8*)(Bs + ldrow * 40 + ldseg) =
        *(const short8*)(BT + (size_t)(n0 + ldrow) * K + k0 + ldseg);
    __syncthreads();
#pragma unroll
    for (int mi = 0; mi < 2; ++mi) {
      bf16x8 a = *(const bf16x8*)(As + (mw + mi * 16 + n16) * 40 + q4 * 8);
#pragma unroll
      for (int ni = 0; ni < 2; ++ni) {
        bf16x8 b = *(const bf16x8*)(Bs + (nw + ni * 16 + n16) * 40 + q4 * 8);
        acc[mi][ni] = __builtin_amdgcn_mfma_f32_16x16x32_bf16(a, b, acc[mi][ni], 0, 0, 0);
      }
    }
    __syncthreads();
  }
#pragma unroll
  for (int mi = 0; mi < 2; ++mi)
#pragma unroll
    for (int ni = 0; ni < 2; ++ni) {
      int col = n0 + nw + ni * 16 + n16;
      float bv = bias[col];
#pragma unroll
      for (int r = 0; r < 4; ++r) {
        int m = m0 + mw + mi * 16 + q4 * 4 + r;
        int orow = ((m >> 13) * 16 + (m & 15)) * 512 + ((m & 8191) >> 4);
        C[(size_t)orow * N + col] = acc[mi][ni][r] + bv;
      }
    }
}

// ---------- LSTM scan — round-0 proven structure + raw-xp double-buffer ----------
// 32 blocks x 256 threads; 4 groups x 8 blocks. U in VGPRs. Sentinel-poll on the
// h data itself (agent scope), block-shared detection + LDS staging (measured
// fastest exchange; round-3's per-wave fragment polling was 3.7x slower).
// NEW vs round-0: xp for step t+1 is loaded RAW (u16, no bf2f -> no forced
// s_waitcnt) into an explicit double buffer (static indices, rule #20), so the
// 16 scattered HBM loads never stall the top of a step; conversion happens at
// the gates, a full step after issue.
#define T_STEPS 512
#define HLSZ (16 * 520)

#define LSTM_STEP(XC, XN, TT)                                                  \
  {                                                                            \
    const int t = (TT);                                                        \
    const int tn = (t + 1) & (T_STEPS - 1);                                    \
    /* prefetch next step's xp as RAW u16; consumed next step */               \
    _Pragma("unroll")                                                          \
    for (int qg = 0; qg < 4; ++qg)                                             \
      _Pragma("unroll")                                                        \
      for (int r = 0; r < 4; ++r)                                              \
        XN[qg * 4 + r] = xp_base[((size_t)(q4 * 4 + r) * T_STEPS + tn) * 2048  \
                                 + qg * 512 + cb + n];                         \
    __asm__ volatile("" ::: "memory");                                         \
    floatx4 acc[4] = {};                                                       \
    if (t > 0) {                                                               \
      const u64* hsrc = (const u64*)(hT_all)                                   \
                        + (size_t)(g * T_STEPS + (t - 1)) * 2048;              \
      u64 v[8];                                                                \
      for (;;) {                                                               \
        _Pragma("unroll")                                                      \
        for (int it = 0; it < 8; ++it)                                         \
          v[it] = __hip_atomic_load(hsrc + it * 256 + tid, __ATOMIC_RELAXED,   \
                                    __HIP_MEMORY_SCOPE_AGENT);                 \
        bool ok = true;                                                        \
        _Pragma("unroll")                                                      \
        for (int it = 0; it < 8; ++it) ok &= (v[it] != ~0ull);                 \
        if (ok) break;                                                         \
      }                                                                        \
      __asm__ volatile("" ::: "memory");                                       \
      u16* buf = hls + ((t - 1) & 1) * HLSZ;                                   \
      _Pragma("unroll")                                                        \
      for (int it = 0; it < 8; ++it) {                                         \
        int idx = it * 256 + tid;                                              \
        int tile = idx >> 6, w = idx & 63;                                     \
        *(u64*)(buf + (w >> 2) * 520 + tile * 16 + (w & 3) * 4) = v[it];       \
      }                                                                        \
      __syncthreads();                                                         \
      _Pragma("unroll")                                                        \
      for (int kt = 0; kt < 16; ++kt) {                                        \
        bf16x8 a = *(const bf16x8*)(buf + n * 520 + kt * 32 + q4 * 8);         \
        acc[0] = __builtin_amdgcn_mfma_f32_16x16x32_bf16(a, u[0][kt], acc[0], 0, 0, 0); \
        acc[1] = __builtin_amdgcn_mfma_f32_16x16x32_bf16(a, u[1][kt], acc[1], 0, 0, 0); \
        acc[2] = __builtin_amdgcn_mfma_f32_16x16x32_bf16(a, u[2][kt], acc[2], 0, 0, 0); \
        acc[3] = __builtin_amdgcn_mfma_f32_16x16x32_bf16(a, u[3][kt], acc[3], 0, 0, 0); \
      }                                                                        \
    }                                                                          \
    _Pragma("unroll")                                                          \
    for (int r = 0; r < 4; ++r) {                                              \
      float gi = sigm(acc[0][r] + bf2f(XC[r]));                                \
      float gf = sigm(acc[1][r] + bf2f(XC[4 + r]));                            \
      float gg = tanh_f(acc[2][r] + bf2f(XC[8 + r]));                          \
      float go = sigm(acc[3][r] + bf2f(XC[12 + r]));                           \
      float cn = gf * cst[r] + gi * gg;                                        \
      cst[r] = cn;                                                             \
      float hv = go * tanh_f(cn);                                              \
      int row = q4 * 4 + r;                                                    \
      hp[row * 16 + n] = f2bf(hv);                                             \
      if (t == T_STEPS - 1) {                                                  \
        out_hT[(g * 16 + row) * 512 + cb + n] = hv;                            \
        out_cT[(g * 16 + row) * 512 + cb + n] = cn;                            \
      }                                                                        \
    }                                                                          \
    __asm__ volatile("s_waitcnt lgkmcnt(0)" ::: "memory");                     \
    {                                                                          \
      u64 v = *(const u64*)(hp + (lane >> 2) * 16 + (lane & 3) * 4);           \
      u64* hdst = (u64*)(hT_all) + (size_t)(g * T_STEPS + t) * 2048            \
                  + p * 64 + lane;                                             \
      __hip_atomic_store(hdst, v, __ATOMIC_RELAXED, __HIP_MEMORY_SCOPE_AGENT); \
    }                                                                          \
  }

__global__ __launch_bounds__(256, 1) void lstm_scan(
    const u16* __restrict__ xp,     // [64, 512, 2048] bf16
    const u16* __restrict__ UT,     // [2048, 512] bf16
    u16* __restrict__ hT_all,       // [4][512][32][16][16] bf16, sentinel-filled
    float* __restrict__ out_hT,     // [64,512] f32
    float* __restrict__ out_cT) {   // [64,512] f32
  const int bi = blockIdx.x;
  const int g = (bi & 7) >> 1;
  const int wgi = ((bi & 1) << 2) | (bi >> 3);
  const int tid = threadIdx.x;
  const int wave = tid >> 6;
  const int lane = tid & 63;
  const int n = lane & 15;
  const int q4 = lane >> 4;
  const int cb = wgi * 64 + wave * 16;   // wave's h-col base
  const int p = wgi * 4 + wave;          // tile index in group, 0..31

  __shared__ __align__(16) u16 hls[2 * HLSZ];  // parity-double-buffered stage
  __shared__ __align__(8) u16 hstw[4 * 256];   // per-wave 16x16 transpose patch
  u16* hp = hstw + wave * 256;

  // Preload U fragments (B-operand layout)
  bf16x8 u[4][16];
#pragma unroll
  for (int qg = 0; qg < 4; ++qg) {
    const u16* up = UT + (size_t)(qg * 512 + cb + n) * 512;
#pragma unroll
    for (int kt = 0; kt < 16; ++kt)
      u[qg][kt] = *(const bf16x8*)(up + kt * 32 + q4 * 8);
  }

  float cst[4] = {0.f, 0.f, 0.f, 0.f};
  const u16* xp_base = xp + (size_t)(g * 16) * T_STEPS * 2048;

  // prologue: raw xp for t=0
  u16 xa[16], xb[16];
#pragma unroll
  for (int qg = 0; qg < 4; ++qg)
#pragma unroll
    for (int r = 0; r < 4; ++r)
      xa[qg * 4 + r] = xp_base[((size_t)(q4 * 4 + r) * T_STEPS + 0) * 2048
                               + qg * 512 + cb + n];

#pragma unroll 1
  for (int t2 = 0; t2 < T_STEPS; t2 += 2) {
    LSTM_STEP(xa, xb, t2)
    LSTM_STEP(xb, xa, t2 + 1)
  }
}

// ---------- launch ----------
extern "C" void kernel_launch(void* const* d_in, const int* in_sizes, int n_in,
                              void* d_out, int out_size, void* d_ws, size_t ws_size,
                              hipStream_t stream) {
  (void)in_sizes; (void)n_in; (void)out_size; (void)ws_size;
  const float* x    = (const float*)d_in[0]; // [64,512,256] f32
  const float* W    = (const float*)d_in[1]; // [256,2048] f32
  const float* U    = (const float*)d_in[2]; // [512,2048] f32
  const float* bias = (const float*)d_in[3]; // [2048] f32
  const float* Wl   = (const float*)d_in[4]; // [512,256] f32
  const float* bl   = (const float*)d_in[5]; // [256] f32
  float* out = (float*)d_out;                // [64,512,256] ++ hT[64,512] ++ cT[64,512]
  char* ws = (char*)d_ws;

  u16* xp     = (u16*)(ws + 0);            // 134,217,728 B
  u16* UT     = (u16*)(ws + 134217728);    //   2,097,152 B
  u16* WT     = (u16*)(ws + 136314880);    //   1,048,576 B
  u16* WlT    = (u16*)(ws + 137363456);    //     262,144 B
  u16* hT_all = (u16*)(ws + 137625600);    //  33,554,432 B  [4][512][32][16][16]

  // sentinel-fill h slots (0xFFFF bf16 = NaN, impossible as an h value)
  hipMemsetAsync(hT_all, 0xFF, 33554432, stream);

  transpose_f32_bf16<<<dim3(2048 / 32, 256 / 32), dim3(32, 8), 0, stream>>>(W, WT, 256, 2048);
  transpose_f32_bf16<<<dim3(2048 / 32, 512 / 32), dim3(32, 8), 0, stream>>>(U, UT, 512, 2048);
  transpose_f32_bf16<<<dim3(256 / 32, 512 / 32), dim3(32, 8), 0, stream>>>(Wl, WlT, 512, 256);

  // x_proj = x @ W + bias : [32768,256] x [256,2048] -> bf16
  gemm_a32_bt<<<dim3(2048 / 64, 32768 / 64), 256, 0, stream>>>(x, WT, bias, xp, 32768, 2048, 256);

  // sequential LSTM scan (writes hT_all in blocked [g][t][tile][row][col] layout)
  lstm_scan<<<32, 256, 0, stream>>>(xp, UT, hT_all,
                                    out + 8388608, out + 8421376);

  // out = hseq @ Wl + bl, reading blocked layout, remapping output rows
  gemm_bt_f32out_perm<<<dim3(256 / 64, 32768 / 64), 256, 0, stream>>>(
      hT_all, WlT, bl, out, 32768, 256, 512);
}

// Round 5
// 1440.888 us; speedup vs baseline: 3.1304x; 1.0403x over previous
//
#include <hip/hip_runtime.h>
#include <stdint.h>

typedef uint16_t u16;
typedef uint32_t u32;
typedef unsigned long long u64;
typedef __attribute__((ext_vector_type(8))) __bf16 bf16x8;
typedef __attribute__((ext_vector_type(8))) short short8;
typedef __attribute__((ext_vector_type(4))) float floatx4;

// ---------- helpers ----------
__device__ __forceinline__ float bf2f(u16 u) {
  union { u32 i; float f; } v; v.i = ((u32)u) << 16; return v.f;
}
__device__ __forceinline__ u16 f2bf(float f) {
  union { float f; u32 i; } v; v.f = f;
  u32 i = v.i;
  return (u16)((i + 0x7FFFu + ((i >> 16) & 1u)) >> 16); // RTNE
}
__device__ __forceinline__ float sigm(float x) { return 1.f / (1.f + __expf(-x)); }
__device__ __forceinline__ float tanh_f(float x) {
  x = fminf(15.f, fmaxf(-15.f, x));
  float e = __expf(2.f * x);
  return (e - 1.f) / (e + 1.f);
}

// ---------- fp32 -> bf16 transpose: src[R][C] f32 -> dst[C][R] bf16 ----------
__global__ void transpose_f32_bf16(const float* __restrict__ src, u16* __restrict__ dst,
                                   int R, int C) {
  __shared__ u16 tile[32][33];
  int x = blockIdx.x * 32 + threadIdx.x;
#pragma unroll
  for (int j = 0; j < 4; ++j) {
    int y = blockIdx.y * 32 + threadIdx.y + j * 8;
    if (x < C && y < R) tile[threadIdx.y + j * 8][threadIdx.x] = f2bf(src[(size_t)y * C + x]);
  }
  __syncthreads();
  int x2 = blockIdx.y * 32 + threadIdx.x;
#pragma unroll
  for (int j = 0; j < 4; ++j) {
    int y2 = blockIdx.x * 32 + threadIdx.y + j * 8;
    if (x2 < R && y2 < C) dst[(size_t)y2 * R + x2] = tile[threadIdx.x][threadIdx.y + j * 8];
  }
}

// ================== fused kernel: scan (blocks 0-31) + workers (32-255) ==================
// Workers phase A: xp = x@W + bias, tile jobs in t-chunk-ascending order; agent
//   (write-through) stores; per-(b,tchunk) counter bumped after vmcnt(0)+barrier.
//   Scan gates its xp prefetch on ctr==32 at 64-step boundaries only.
// Workers phase B: out = hseq@Wl + bl, jobs in t-ascending order; A-tiles read with
//   agent-scope sentinel-validated u64 loads (same discipline as the scan's h poll;
//   h stores are u64-atomic so a non-sentinel u64 is always final data).
// Deadlock-free: grid 256 <= 256 CUs (all resident; scan dispatched first);
// DAG producers -> scan -> consumers; all polls on monotone conditions.
#define T_STEPS 512
#define HLSZ (16 * 520)
#define NWORK 224

#define LSTM_STEP(XC, XN, TT)                                                  \
  {                                                                            \
    const int t = (TT);                                                        \
    const int tn = (t + 1) & (T_STEPS - 1);                                    \
    /* gate: entering a new 64-step xp chunk -> wait for its producers */      \
    if (((tn) & 63) == 0 && t < T_STEPS - 1) {                                 \
      _Pragma("unroll")                                                        \
      for (int r = 0; r < 4; ++r) {                                            \
        const u32* cc = ctr + ((g * 16 + q4 * 4 + r) * 8 + (tn >> 6));         \
        while (__hip_atomic_load(cc, __ATOMIC_RELAXED,                         \
                                 __HIP_MEMORY_SCOPE_AGENT) < 32u)              \
          __builtin_amdgcn_s_sleep(2);                                         \
      }                                                                        \
      __asm__ volatile("" ::: "memory");                                       \
    }                                                                          \
    /* prefetch next step's xp as RAW u16; consumed next step */               \
    _Pragma("unroll")                                                          \
    for (int qg = 0; qg < 4; ++qg)                                             \
      _Pragma("unroll")                                                        \
      for (int r = 0; r < 4; ++r)                                              \
        XN[qg * 4 + r] = xp_base[((size_t)(q4 * 4 + r) * T_STEPS + tn) * 2048  \
                                 + qg * 512 + cb + n];                         \
    __asm__ volatile("" ::: "memory");                                         \
    floatx4 acc[4] = {};                                                       \
    if (t > 0) {                                                               \
      const u64* hsrc = (const u64*)(hT_all)                                   \
                        + (size_t)(g * T_STEPS + (t - 1)) * 2048;              \
      u64 v[8];                                                                \
      for (;;) {                                                               \
        _Pragma("unroll")                                                      \
        for (int it = 0; it < 8; ++it)                                         \
          v[it] = __hip_atomic_load(hsrc + it * 256 + tid, __ATOMIC_RELAXED,   \
                                    __HIP_MEMORY_SCOPE_AGENT);                 \
        bool ok = true;                                                        \
        _Pragma("unroll")                                                      \
        for (int it = 0; it < 8; ++it) ok &= (v[it] != ~0ull);                 \
        if (ok) break;                                                         \
      }                                                                        \
      __asm__ volatile("" ::: "memory");                                       \
      u16* buf = hls + ((t - 1) & 1) * HLSZ;                                   \
      _Pragma("unroll")                                                        \
      for (int it = 0; it < 8; ++it) {                                         \
        int idx = it * 256 + tid;                                              \
        int tile = idx >> 6, w = idx & 63;                                     \
        *(u64*)(buf + (w >> 2) * 520 + tile * 16 + (w & 3) * 4) = v[it];       \
      }                                                                        \
      __syncthreads();                                                         \
      _Pragma("unroll")                                                        \
      for (int kt = 0; kt < 16; ++kt) {                                        \
        bf16x8 a = *(const bf16x8*)(buf + n * 520 + kt * 32 + q4 * 8);         \
        acc[0] = __builtin_amdgcn_mfma_f32_16x16x32_bf16(a, u[0][kt], acc[0], 0, 0, 0); \
        acc[1] = __builtin_amdgcn_mfma_f32_16x16x32_bf16(a, u[1][kt], acc[1], 0, 0, 0); \
        acc[2] = __builtin_amdgcn_mfma_f32_16x16x32_bf16(a, u[2][kt], acc[2], 0, 0, 0); \
        acc[3] = __builtin_amdgcn_mfma_f32_16x16x32_bf16(a, u[3][kt], acc[3], 0, 0, 0); \
      }                                                                        \
    }                                                                          \
    _Pragma("unroll")                                                          \
    for (int r = 0; r < 4; ++r) {                                              \
      float gi = sigm(acc[0][r] + bf2f(XC[r]));                                \
      float gf = sigm(acc[1][r] + bf2f(XC[4 + r]));                            \
      float gg = tanh_f(acc[2][r] + bf2f(XC[8 + r]));                          \
      float go = sigm(acc[3][r] + bf2f(XC[12 + r]));                           \
      float cn = gf * cst[r] + gi * gg;                                        \
      cst[r] = cn;                                                             \
      float hv = go * tanh_f(cn);                                              \
      int row = q4 * 4 + r;                                                    \
      hp[row * 16 + n] = f2bf(hv);                                             \
      if (t == T_STEPS - 1) {                                                  \
        out_hT[(g * 16 + row) * 512 + cb + n] = hv;                            \
        out_cT[(g * 16 + row) * 512 + cb + n] = cn;                            \
      }                                                                        \
    }                                                                          \
    __asm__ volatile("s_waitcnt lgkmcnt(0)" ::: "memory");                     \
    {                                                                          \
      u64 v = *(const u64*)(hp + (lane >> 2) * 16 + (lane & 3) * 4);           \
      u64* hdst = (u64*)(hT_all) + (size_t)(g * T_STEPS + t) * 2048            \
                  + p * 64 + lane;                                             \
      __hip_atomic_store(hdst, v, __ATOMIC_RELAXED, __HIP_MEMORY_SCOPE_AGENT); \
    }                                                                          \
  }

__global__ __launch_bounds__(256, 1) void fused_lstm(
    const float* __restrict__ x,    // [32768, 256] f32 (rows m = b*512 + t)
    const u16* __restrict__ WT,     // [2048, 256] bf16
    const float* __restrict__ bias, // [2048] f32
    u16* __restrict__ xp,           // [32768, 2048] bf16 (produced here)
    const u16* __restrict__ UT,     // [2048, 512] bf16
    u16* __restrict__ hT_all,       // [4][512][32][16][16] bf16, sentinel-filled
    const u16* __restrict__ WlT,    // [256, 512] bf16
    const float* __restrict__ bl,   // [256] f32
    float* __restrict__ outC,       // [32768, 256] f32 (permuted-row final out)
    float* __restrict__ out_hT,     // [64,512] f32
    float* __restrict__ out_cT,     // [64,512] f32
    u32* __restrict__ ctr) {        // [64][8] job counters, zero-filled
  __shared__ __align__(16) u16 smem[2 * HLSZ + 4 * 256];
  const int bi = blockIdx.x;
  const int tid = threadIdx.x;

  if (bi >= 32) {
    // =================== WORKER ===================
    u16* As = smem;
    u16* Bs = smem + 64 * 40;
    const int wid = bi - 32;
    const int wave = tid >> 6, lane = tid & 63;
    const int q4 = lane >> 4, n16 = lane & 15;
    const int mw = (wave >> 1) * 32, nw = (wave & 1) * 32;
    const int ldrow = tid >> 2, ldseg = (tid & 3) * 8;

    // ---- phase A: xp jobs, t-chunk-major ----
    for (int j = wid; j < 16384; j += NWORK) {
      const int tch = j >> 11;
      const int rem = j & 2047;
      const int b = rem >> 5, nt = rem & 31;
      const int m0 = b * 512 + tch * 64, n0 = nt * 64;
      floatx4 acc[2][2] = {};
      for (int k0 = 0; k0 < 256; k0 += 32) {
        const float* ap = x + (size_t)(m0 + ldrow) * 256 + k0 + ldseg;
        floatx4 a0 = *(const floatx4*)ap;
        floatx4 a1 = *(const floatx4*)(ap + 4);
        short8 s;
        s[0] = (short)f2bf(a0[0]); s[1] = (short)f2bf(a0[1]);
        s[2] = (short)f2bf(a0[2]); s[3] = (short)f2bf(a0[3]);
        s[4] = (short)f2bf(a1[0]); s[5] = (short)f2bf(a1[1]);
        s[6] = (short)f2bf(a1[2]); s[7] = (short)f2bf(a1[3]);
        *(short8*)(As + ldrow * 40 + ldseg) = s;
        *(short8*)(Bs + ldrow * 40 + ldseg) =
            *(const short8*)(WT + (size_t)(n0 + ldrow) * 256 + k0 + ldseg);
        __syncthreads();
#pragma unroll
        for (int mi = 0; mi < 2; ++mi) {
          bf16x8 a = *(const bf16x8*)(As + (mw + mi * 16 + n16) * 40 + q4 * 8);
#pragma unroll
          for (int ni = 0; ni < 2; ++ni) {
            bf16x8 bb = *(const bf16x8*)(Bs + (nw + ni * 16 + n16) * 40 + q4 * 8);
            acc[mi][ni] = __builtin_amdgcn_mfma_f32_16x16x32_bf16(a, bb, acc[mi][ni], 0, 0, 0);
          }
        }
        __syncthreads();
      }
      // epilogue: agent (write-through) stores so the scan's XCD sees them
#pragma unroll
      for (int mi = 0; mi < 2; ++mi)
#pragma unroll
        for (int ni = 0; ni < 2; ++ni) {
          int col = n0 + nw + ni * 16 + n16;
          float bv = bias[col];
#pragma unroll
          for (int r = 0; r < 4; ++r) {
            int m = m0 + mw + mi * 16 + q4 * 4 + r;
            u16 val = f2bf(acc[mi][ni][r] + bv);
            __hip_atomic_store(xp + (size_t)m * 2048 + col, val,
                               __ATOMIC_RELAXED, __HIP_MEMORY_SCOPE_AGENT);
          }
        }
      __asm__ volatile("s_waitcnt vmcnt(0)" ::: "memory");
      __syncthreads();
      if (tid == 0)
        __hip_atomic_fetch_add(ctr + b * 8 + tch, 1u,
                               __ATOMIC_RELAXED, __HIP_MEMORY_SCOPE_AGENT);
    }

    // ---- phase B: final GEMM jobs, t-ascending; sentinel-validated A loads ----
    for (int j = wid; j < 2048; j += NWORK) {
      const int tb = j >> 4, g2 = (j >> 2) & 3, nt = j & 3;
      const int m0 = g2 * 8192 + tb * 64, n0 = nt * 64;
      const int mm = m0 + ldrow;
      const size_t slot = ((size_t)((mm >> 13) * 512 + ((mm & 8191) >> 4))) * 8192
                          + (mm & 15) * 16;
      floatx4 acc[2][2] = {};
      for (int k0 = 0; k0 < 512; k0 += 32) {
        int kk = k0 + ldseg;
        const u64* ap64 = (const u64*)(hT_all + slot + (kk >> 4) * 256 + (kk & 15));
        u64 lo, hi;
        for (;;) {
          lo = __hip_atomic_load(ap64, __ATOMIC_RELAXED, __HIP_MEMORY_SCOPE_AGENT);
          hi = __hip_atomic_load(ap64 + 1, __ATOMIC_RELAXED, __HIP_MEMORY_SCOPE_AGENT);
          if (lo != ~0ull && hi != ~0ull) break;
          __builtin_amdgcn_s_sleep(8);
        }
        *(u64*)(As + ldrow * 40 + ldseg) = lo;
        *(u64*)(As + ldrow * 40 + ldseg + 4) = hi;
        *(short8*)(Bs + ldrow * 40 + ldseg) =
            *(const short8*)(WlT + (size_t)(n0 + ldrow) * 512 + k0 + ldseg);
        __syncthreads();
#pragma unroll
        for (int mi = 0; mi < 2; ++mi) {
          bf16x8 a = *(const bf16x8*)(As + (mw + mi * 16 + n16) * 40 + q4 * 8);
#pragma unroll
          for (int ni = 0; ni < 2; ++ni) {
            bf16x8 bb = *(const bf16x8*)(Bs + (nw + ni * 16 + n16) * 40 + q4 * 8);
            acc[mi][ni] = __builtin_amdgcn_mfma_f32_16x16x32_bf16(a, bb, acc[mi][ni], 0, 0, 0);
          }
        }
        __syncthreads();
      }
#pragma unroll
      for (int mi = 0; mi < 2; ++mi)
#pragma unroll
        for (int ni = 0; ni < 2; ++ni) {
          int col = n0 + nw + ni * 16 + n16;
          float bv = bl[col];
#pragma unroll
          for (int r = 0; r < 4; ++r) {
            int m = m0 + mw + mi * 16 + q4 * 4 + r;
            int orow = ((m >> 13) * 16 + (m & 15)) * 512 + ((m & 8191) >> 4);
            outC[(size_t)orow * 256 + col] = acc[mi][ni][r] + bv;
          }
        }
    }
    return;
  }

  // =================== SCAN (round-0/4 proven structure + ctr gates) ===================
  u16* hls = smem;                 // parity-double-buffered stage
  u16* hstw = smem + 2 * HLSZ;     // per-wave 16x16 transpose patch
  const int g = (bi & 7) >> 1;
  const int wgi = ((bi & 1) << 2) | (bi >> 3);
  const int wave = tid >> 6;
  const int lane = tid & 63;
  const int n = lane & 15;
  const int q4 = lane >> 4;
  const int cb = wgi * 64 + wave * 16;   // wave's h-col base
  const int p = wgi * 4 + wave;          // tile index in group, 0..31
  u16* hp = hstw + wave * 256;

  // Preload U fragments (B-operand layout)
  bf16x8 u[4][16];
#pragma unroll
  for (int qg = 0; qg < 4; ++qg) {
    const u16* up = UT + (size_t)(qg * 512 + cb + n) * 512;
#pragma unroll
    for (int kt = 0; kt < 16; ++kt)
      u[qg][kt] = *(const bf16x8*)(up + kt * 32 + q4 * 8);
  }

  float cst[4] = {0.f, 0.f, 0.f, 0.f};
  const u16* xp_base = xp + (size_t)(g * 16) * T_STEPS * 2048;

  // prologue: gate on t-chunk 0, then raw xp for t=0
#pragma unroll
  for (int r = 0; r < 4; ++r) {
    const u32* cc = ctr + ((g * 16 + q4 * 4 + r) * 8 + 0);
    while (__hip_atomic_load(cc, __ATOMIC_RELAXED, __HIP_MEMORY_SCOPE_AGENT) < 32u)
      __builtin_amdgcn_s_sleep(2);
  }
  __asm__ volatile("" ::: "memory");

  u16 xa[16], xb[16];
#pragma unroll
  for (int qg = 0; qg < 4; ++qg)
#pragma unroll
    for (int r = 0; r < 4; ++r)
      xa[qg * 4 + r] = xp_base[((size_t)(q4 * 4 + r) * T_STEPS + 0) * 2048
                               + qg * 512 + cb + n];

#pragma unroll 1
  for (int t2 = 0; t2 < T_STEPS; t2 += 2) {
    LSTM_STEP(xa, xb, t2)
    LSTM_STEP(xb, xa, t2 + 1)
  }
}

// ---------- launch ----------
extern "C" void kernel_launch(void* const* d_in, const int* in_sizes, int n_in,
                              void* d_out, int out_size, void* d_ws, size_t ws_size,
                              hipStream_t stream) {
  (void)in_sizes; (void)n_in; (void)out_size; (void)ws_size;
  const float* x    = (const float*)d_in[0]; // [64,512,256] f32
  const float* W    = (const float*)d_in[1]; // [256,2048] f32
  const float* U    = (const float*)d_in[2]; // [512,2048] f32
  const float* bias = (const float*)d_in[3]; // [2048] f32
  const float* Wl   = (const float*)d_in[4]; // [512,256] f32
  const float* bl   = (const float*)d_in[5]; // [256] f32
  float* out = (float*)d_out;                // [64,512,256] ++ hT[64,512] ++ cT[64,512]
  char* ws = (char*)d_ws;

  u16* xp     = (u16*)(ws + 0);            // 134,217,728 B
  u16* UT     = (u16*)(ws + 134217728);    //   2,097,152 B
  u16* WT     = (u16*)(ws + 136314880);    //   1,048,576 B
  u16* WlT    = (u16*)(ws + 137363456);    //     262,144 B
  u16* hT_all = (u16*)(ws + 137625600);    //  33,554,432 B  [4][512][32][16][16]

  // ctr (2 KB) lives in the FIRST 2 KB of out_hT: dead after the scan's last
  // gate (t=448) and fully overwritten by the scan's t=511 epilogue.
  u32* ctr = (u32*)(out + 8388608);

  // sentinel-fill h slots (0xFFFF bf16 = NaN, impossible as an h value);
  // zero the xp job counters.
  hipMemsetAsync(hT_all, 0xFF, 33554432, stream);
  hipMemsetAsync(ctr, 0x00, 2048, stream);

  transpose_f32_bf16<<<dim3(2048 / 32, 256 / 32), dim3(32, 8), 0, stream>>>(W, WT, 256, 2048);
  transpose_f32_bf16<<<dim3(2048 / 32, 512 / 32), dim3(32, 8), 0, stream>>>(U, UT, 512, 2048);
  transpose_f32_bf16<<<dim3(256 / 32, 512 / 32), dim3(32, 8), 0, stream>>>(Wl, WlT, 512, 256);

  // fused: scan (32 blocks) + xp producers / final-GEMM consumers (224 blocks)
  fused_lstm<<<256, 256, 0, stream>>>(x, WT, bias, xp, UT, hT_all, WlT, bl,
                                      out, out + 8388608, out + 8421376, ctr);
}